// Round 5
// baseline (374.728 us; speedup 1.0000x reference)
//
#include <hip/hip_runtime.h>
#include <hip/hip_fp16.h>

// N_NODES=100000, N_EDGES=50000, NNZ=1600000, dims 128->128->16, fp32 I/O.
// Message path fp16 (flat [row][128]), accumulate fp32. CSR: LDS-only counting sort.
// F=128 aggs: row x 16B-chunk dwordx4 gathers (R10 structure).
// R12: staged pairs packed to u32; nnbr u16. (374 -> 364.5 us)
// R13: agg128 accumulate via v_fma_mix_f32 (fp16 src, fp32 acc -- numerically
// identical to cvt+add, half the VALU ops) + 8-deep row unroll for MLP.
// R14: resubmit (R13 bench hit infra failure: container acquire failed twice).

#define N_EDGES_C 50000
#define F1 128
#define F2 16
#define CHUNK 4096
#define EBIN_SHIFT 7
#define NBIN_SHIFT 8
#define EBINS 391
#define NBINS 391

typedef __attribute__((ext_vector_type(8))) _Float16 half8;
typedef __attribute__((ext_vector_type(4))) float f32x4;
typedef unsigned short ushort16_t;

// ---------------- CSR build ----------------

__global__ __launch_bounds__(256) void hist_chunk_kernel(
    const int* __restrict__ node_idx, const int* __restrict__ edge_idx,
    int* __restrict__ echunkcnt, int* __restrict__ nchunkcnt, int nnz) {
  __shared__ int ebc[EBINS], nbc[NBINS];
  const int t = threadIdx.x;
  for (int b = t; b < EBINS; b += 256) ebc[b] = 0;
  for (int b = t; b < NBINS; b += 256) nbc[b] = 0;
  __syncthreads();
  const int base = blockIdx.x * CHUNK;
  int end = base + CHUNK; if (end > nnz) end = nnz;
  for (int i = base + t; i < end; i += 256) {
    atomicAdd(&ebc[edge_idx[i] >> EBIN_SHIFT], 1);
    atomicAdd(&nbc[node_idx[i] >> NBIN_SHIFT], 1);
  }
  __syncthreads();
  const int nC = gridDim.x;
  for (int b = t; b < EBINS; b += 256) echunkcnt[b * nC + blockIdx.x] = ebc[b];
  for (int b = t; b < NBINS; b += 256) nchunkcnt[b * nC + blockIdx.x] = nbc[b];
}

__global__ __launch_bounds__(256) void cscan_p1_kernel(
    const int* __restrict__ ecc, const int* __restrict__ ncc,
    int* __restrict__ epart, int* __restrict__ npart,
    int Le, int Ln, int nbE) {
  __shared__ int red[256];
  const int t = threadIdx.x;
  const int b = blockIdx.x;
  const int* src; int L; int* dst; int bb;
  if (b < nbE) { src = ecc; L = Le; dst = epart; bb = b; }
  else         { src = ncc; L = Ln; dst = npart; bb = b - nbE; }
  int base = bb * 1024 + t * 4;
  int s = 0;
#pragma unroll
  for (int j = 0; j < 4; ++j) { int i = base + j; if (i < L) s += src[i]; }
  red[t] = s;
  __syncthreads();
  for (int d = 128; d > 0; d >>= 1) {
    if (t < d) red[t] += red[t + d];
    __syncthreads();
  }
  if (t == 0) dst[bb] = red[0];
}

__global__ __launch_bounds__(256) void cscan_p2_kernel(
    int* __restrict__ epart, int* __restrict__ npart,
    int* __restrict__ ebinbase, int* __restrict__ nbinbase,
    int nbE, int nbN, int nnz) {
  __shared__ int se[256], sn[256];
  const int t = threadIdx.x;
  se[t] = (t < nbE) ? epart[t] : 0;
  sn[t] = (t < nbN) ? npart[t] : 0;
  __syncthreads();
  for (int d = 1; d < 256; d <<= 1) {
    int ve = (t >= d) ? se[t - d] : 0;
    int vn = (t >= d) ? sn[t - d] : 0;
    __syncthreads();
    se[t] += ve; sn[t] += vn;
    __syncthreads();
  }
  if (t < nbE) epart[t] = (t > 0) ? se[t - 1] : 0;
  if (t < nbN) npart[t] = (t > 0) ? sn[t - 1] : 0;
  if (t == 0) { ebinbase[EBINS] = nnz; nbinbase[NBINS] = nnz; }
}

__global__ __launch_bounds__(256) void cscan_p3_kernel(
    const int* __restrict__ ecc, const int* __restrict__ ncc,
    const int* __restrict__ epart, const int* __restrict__ npart,
    int* __restrict__ erunoff, int* __restrict__ nrunoff,
    int* __restrict__ ebinbase, int* __restrict__ nbinbase,
    int Le, int Ln, int nbE, int nC) {
  __shared__ int red[256];
  const int t = threadIdx.x;
  const int b = blockIdx.x;
  const int* src; const int* part; int L; int* ro; int* bba; int bb;
  if (b < nbE) { src = ecc; part = epart; L = Le; ro = erunoff; bba = ebinbase; bb = b; }
  else         { src = ncc; part = npart; L = Ln; ro = nrunoff; bba = nbinbase; bb = b - nbE; }
  int base = bb * 1024 + t * 4;
  int v[4]; int s = 0;
#pragma unroll
  for (int j = 0; j < 4; ++j) { int i = base + j; v[j] = (i < L) ? src[i] : 0; s += v[j]; }
  red[t] = s;
  __syncthreads();
  for (int d = 1; d < 256; d <<= 1) {
    int x = (t >= d) ? red[t - d] : 0;
    __syncthreads();
    red[t] += x;
    __syncthreads();
  }
  int run = part[bb] + ((t > 0) ? red[t - 1] : 0);
#pragma unroll
  for (int j = 0; j < 4; ++j) {
    int i = base + j;
    if (i < L) {
      ro[i] = run;
      if (i % nC == 0) bba[i / nC] = run;
      run += v[j];
    }
  }
}

// stage: pack pairs into u32. e-side: (n<<7)|(e&127)  [17+7=24 bits]
//                             n-side: (e<<8)|(n&255)  [16+8=24 bits]

__global__ __launch_bounds__(256) void stage_kernel(
    const int* __restrict__ node_idx, const int* __restrict__ edge_idx,
    const int* __restrict__ erunoff, const int* __restrict__ nrunoff,
    unsigned* __restrict__ epairs, unsigned* __restrict__ npairs, int nnz) {
  __shared__ int ecur[EBINS], ncur[NBINS];
  const int t = threadIdx.x;
  const int nC = gridDim.x;
  for (int b = t; b < EBINS; b += 256) ecur[b] = erunoff[b * nC + blockIdx.x];
  for (int b = t; b < NBINS; b += 256) ncur[b] = nrunoff[b * nC + blockIdx.x];
  __syncthreads();
  const int base = blockIdx.x * CHUNK;
  int end = base + CHUNK; if (end > nnz) end = nnz;
  for (int i = base + t; i < end; i += 256) {
    int e = edge_idx[i];
    int n = node_idx[i];
    int p = atomicAdd(&ecur[e >> EBIN_SHIFT], 1);
    epairs[p] = ((unsigned)n << 7) | (unsigned)(e & 127);
    int q = atomicAdd(&ncur[n >> NBIN_SHIFT], 1);
    npairs[q] = ((unsigned)e << 8) | (unsigned)(n & 255);
  }
}

__global__ __launch_bounds__(256) void bin_scatter_kernel(
    const unsigned* __restrict__ epairs, const unsigned* __restrict__ npairs,
    const int* __restrict__ ebinbase, const int* __restrict__ nbinbase,
    int* __restrict__ eoff, int* __restrict__ noff,
    int* __restrict__ enbr, ushort16_t* __restrict__ nnbr,
    int n_edges, int n_nodes) {
  __shared__ int cnt[256];
  __shared__ int scn[256];
  const int bid = blockIdx.x;
  const int t = threadIdx.x;
  if (bid < EBINS) {
    const int e0 = bid << EBIN_SHIFT;
    const int ne = min(1 << EBIN_SHIFT, n_edges - e0);
    const int beg = ebinbase[bid], end = ebinbase[bid + 1];
    if (t < 128) cnt[t] = 0;
    __syncthreads();
    for (int j = beg + t; j < end; j += 256) atomicAdd(&cnt[epairs[j] & 127u], 1);
    __syncthreads();
    if (t < 128) scn[t] = cnt[t];
    __syncthreads();
    for (int d = 1; d < 128; d <<= 1) {
      int x = 0;
      if (t < 128 && t >= d) x = scn[t - d];
      __syncthreads();
      if (t < 128) scn[t] += x;
      __syncthreads();
    }
    int pos0 = 0;
    if (t < 128) {
      int excl = (t > 0) ? scn[t - 1] : 0;
      pos0 = beg + excl;
      if (t < ne) eoff[e0 + t] = pos0;
    }
    __syncthreads();
    if (t < 128) scn[t] = pos0;
    __syncthreads();
    for (int j = beg + t; j < end; j += 256) {
      unsigned p = epairs[j];
      int pos = atomicAdd(&scn[p & 127u], 1);
      enbr[pos] = (int)(p >> 7);
    }
    if (bid == EBINS - 1 && t == 0) eoff[n_edges] = end;
  } else {
    const int b = bid - EBINS;
    const int n0 = b << NBIN_SHIFT;
    const int nn = min(1 << NBIN_SHIFT, n_nodes - n0);
    const int beg = nbinbase[b], end = nbinbase[b + 1];
    cnt[t] = 0;
    __syncthreads();
    for (int j = beg + t; j < end; j += 256) atomicAdd(&cnt[npairs[j] & 255u], 1);
    __syncthreads();
    scn[t] = cnt[t];
    __syncthreads();
    for (int d = 1; d < 256; d <<= 1) {
      int x = (t >= d) ? scn[t - d] : 0;
      __syncthreads();
      scn[t] += x;
      __syncthreads();
    }
    int excl = (t > 0) ? scn[t - 1] : 0;
    int pos0 = beg + excl;
    if (t < nn) noff[n0 + t] = pos0;
    __syncthreads();
    scn[t] = pos0;
    __syncthreads();
    for (int j = beg + t; j < end; j += 256) {
      unsigned p = npairs[j];
      int pos = atomicAdd(&scn[p & 255u], 1);
      nnbr[pos] = (ushort16_t)(p >> 8);   // edge id < 50000 -> u16
    }
    if (bid == EBINS + NBINS - 1 && t == 0) noff[n_nodes] = end;
  }
}

// ---------------- W1 transpose+convert: W1t16[n][k] = fp16(W1[k][n]) ----------------

__global__ __launch_bounds__(256) void w1t_kernel(
    const float* __restrict__ W1, __half* __restrict__ W1t) {
  int i = blockIdx.x * 256 + threadIdx.x;   // 0..16383
  int n = i >> 7, k = i & 127;
  W1t[i] = __float2half(W1[k * 128 + n]);
}

// ---------------- GEMM1 (MFMA): xw16[M x 128] = fp16(x) @ fp16(W1) ----------------
// 256 thr = 4 waves; block tile 64(M) x 128(N); K=128 in 4 chunks of 32.

__global__ __launch_bounds__(256) void gemm1_kernel(
    const float* __restrict__ A, const __half* __restrict__ W1t16,
    __half* __restrict__ C16, int M) {
  __shared__ _Float16 As[64 * 136];
  __shared__ _Float16 Bs[128 * 136];
  const int t = threadIdx.x;
  const int bm = blockIdx.x * 64;

#pragma unroll
  for (int i = 0; i < 8; ++i) {
    int lin = i * 256 + t;
    int row = lin >> 5;
    int c4 = lin & 31;
    int grow = bm + row;
    float4 v = make_float4(0.f, 0.f, 0.f, 0.f);
    if (grow < M) v = *(const float4*)(A + (size_t)grow * 128 + c4 * 4);
    _Float16* dst = &As[row * 136 + c4 * 4];
    dst[0] = (_Float16)v.x; dst[1] = (_Float16)v.y;
    dst[2] = (_Float16)v.z; dst[3] = (_Float16)v.w;
  }
#pragma unroll
  for (int i = 0; i < 8; ++i) {
    int lin = i * 256 + t;
    int n = lin >> 4;
    int c = lin & 15;
    *(float4*)&Bs[n * 136 + c * 8] = *(const float4*)(W1t16 + n * 128 + c * 8);
  }
  __syncthreads();

  const int w = t >> 6;
  const int lane = t & 63;
  const int l16 = lane & 15;
  const int quad = lane >> 4;

  f32x4 acc[8];
#pragma unroll
  for (int n = 0; n < 8; ++n) acc[n] = (f32x4){0.f, 0.f, 0.f, 0.f};

  const _Float16* arow = &As[(w * 16 + l16) * 136 + quad * 8];
#pragma unroll
  for (int kt = 0; kt < 4; ++kt) {
    half8 a = *(const half8*)(arow + kt * 32);
#pragma unroll
    for (int n = 0; n < 8; ++n) {
      half8 b = *(const half8*)&Bs[(n * 16 + l16) * 136 + kt * 32 + quad * 8];
      acc[n] = __builtin_amdgcn_mfma_f32_16x16x32_f16(a, b, acc[n], 0, 0, 0);
    }
  }
  __syncthreads();   // all frag reads done; reuse As as C-staging

  // C/D layout (m89-verified, dtype-independent): col=lane&15, row=quad*4+reg
#pragma unroll
  for (int n = 0; n < 8; ++n) {
#pragma unroll
    for (int r = 0; r < 4; ++r) {
      int row = w * 16 + quad * 4 + r;
      int col = n * 16 + l16;
      As[row * 136 + col] = (_Float16)acc[n][r];
    }
  }
  __syncthreads();

  // coalesced store: 64 rows x 16 chunks of 16B = 1024 / 256 = 4 iters
#pragma unroll
  for (int i = 0; i < 4; ++i) {
    int lin = i * 256 + t;
    int row = lin >> 4;
    int c = lin & 15;
    int grow = bm + row;
    if (grow < M)
      *(float4*)(C16 + (size_t)grow * 128 + c * 8) = *(const float4*)&As[row * 136 + c * 8];
  }
}

// ---------------- F=128 aggregation: row x 16B-chunk dwordx4 gathers ----------------
// Accumulate: v_fma_mix_f32 (fp16 src0, fp32 src1/acc) -- numerically identical
// to cvt_f32_f16 + add_f32, at half the VALU ops. 8 rows in flight per lane.

__device__ __forceinline__ void acc_mix(float* ax, float4 v) {
  const unsigned* w = (const unsigned*)&v;
  const float onef = 1.0f;
#pragma unroll
  for (int q = 0; q < 4; ++q) {
    asm("v_fma_mix_f32 %0, %1, %2, %0 op_sel:[0,0,0] op_sel_hi:[1,0,0]"
        : "+v"(ax[2 * q]) : "v"(w[q]), "v"(onef));
    asm("v_fma_mix_f32 %0, %1, %2, %0 op_sel:[1,0,0] op_sel_hi:[1,0,0]"
        : "+v"(ax[2 * q + 1]) : "v"(w[q]), "v"(onef));
  }
}

__global__ __launch_bounds__(256) void edge_agg128_kernel(
    const float4* __restrict__ feat,
    const int* __restrict__ nbr, const int* __restrict__ off,
    float4* __restrict__ outf, int nseg) {
  int w = (blockIdx.x * 256 + threadIdx.x) >> 6;
  if (w >= nseg) return;
  const int lane = threadIdx.x & 63;
  const int r = lane >> 4;
  const int f = lane & 15;
  int beg = off[w], end = off[w + 1];
  float ax[8];
#pragma unroll
  for (int i = 0; i < 8; ++i) ax[i] = 0.f;
  int k = beg + r;
  for (; k + 28 < end; k += 32) {
    int n0 = nbr[k],      n1 = nbr[k + 4],  n2 = nbr[k + 8],  n3 = nbr[k + 12];
    int n4 = nbr[k + 16], n5 = nbr[k + 20], n6 = nbr[k + 24], n7 = nbr[k + 28];
    float4 v0 = feat[(size_t)n0 * 16 + f];
    float4 v1 = feat[(size_t)n1 * 16 + f];
    float4 v2 = feat[(size_t)n2 * 16 + f];
    float4 v3 = feat[(size_t)n3 * 16 + f];
    float4 v4 = feat[(size_t)n4 * 16 + f];
    float4 v5 = feat[(size_t)n5 * 16 + f];
    float4 v6 = feat[(size_t)n6 * 16 + f];
    float4 v7 = feat[(size_t)n7 * 16 + f];
    acc_mix(ax, v0); acc_mix(ax, v1); acc_mix(ax, v2); acc_mix(ax, v3);
    acc_mix(ax, v4); acc_mix(ax, v5); acc_mix(ax, v6); acc_mix(ax, v7);
  }
  for (; k < end; k += 4) acc_mix(ax, feat[(size_t)nbr[k] * 16 + f]);
#pragma unroll
  for (int i = 0; i < 8; ++i) {
    ax[i] += __shfl_xor(ax[i], 16, 64);
    ax[i] += __shfl_xor(ax[i], 32, 64);
  }
  if (r == 0) {
    float inv = (end > beg) ? 1.f / (float)(end - beg) : 0.f;
    union { float4 f4; __half2 h[4]; } u;
#pragma unroll
    for (int q = 0; q < 4; ++q)
      u.h[q] = __floats2half2_rn(ax[2 * q] * inv, ax[2 * q + 1] * inv);
    outf[(size_t)w * 16 + f] = u.f4;
  }
}

__global__ __launch_bounds__(256) void node_agg128_kernel(
    const float4* __restrict__ feat,
    const ushort16_t* __restrict__ nbr, const int* __restrict__ off,
    const float* __restrict__ bias,
    float4* __restrict__ outf, int nseg) {
  int w = (blockIdx.x * 256 + threadIdx.x) >> 6;
  if (w >= nseg) return;
  const int lane = threadIdx.x & 63;
  const int r = lane >> 4;
  const int f = lane & 15;
  int beg = off[w], end = off[w + 1];
  float ax[8];
#pragma unroll
  for (int i = 0; i < 8; ++i) ax[i] = 0.f;
  int k = beg + r;
  for (; k + 28 < end; k += 32) {
    int e0 = nbr[k],      e1 = nbr[k + 4],  e2 = nbr[k + 8],  e3 = nbr[k + 12];
    int e4 = nbr[k + 16], e5 = nbr[k + 20], e6 = nbr[k + 24], e7 = nbr[k + 28];
    float4 v0 = feat[(size_t)e0 * 16 + f];
    float4 v1 = feat[(size_t)e1 * 16 + f];
    float4 v2 = feat[(size_t)e2 * 16 + f];
    float4 v3 = feat[(size_t)e3 * 16 + f];
    float4 v4 = feat[(size_t)e4 * 16 + f];
    float4 v5 = feat[(size_t)e5 * 16 + f];
    float4 v6 = feat[(size_t)e6 * 16 + f];
    float4 v7 = feat[(size_t)e7 * 16 + f];
    acc_mix(ax, v0); acc_mix(ax, v1); acc_mix(ax, v2); acc_mix(ax, v3);
    acc_mix(ax, v4); acc_mix(ax, v5); acc_mix(ax, v6); acc_mix(ax, v7);
  }
  for (; k < end; k += 4) acc_mix(ax, feat[(size_t)nbr[k] * 16 + f]);
#pragma unroll
  for (int i = 0; i < 8; ++i) {
    ax[i] += __shfl_xor(ax[i], 16, 64);
    ax[i] += __shfl_xor(ax[i], 32, 64);
  }
  if (r == 0) {
    float inv = (end > beg) ? 1.f / (float)(end - beg) : 0.f;
    float4 blo = ((const float4*)bias)[2 * f];
    float4 bhi = ((const float4*)bias)[2 * f + 1];
    float bb[8] = {blo.x, blo.y, blo.z, blo.w, bhi.x, bhi.y, bhi.z, bhi.w};
    union { float4 f4; __half2 h[4]; } u;
#pragma unroll
    for (int q = 0; q < 4; ++q) {
      float hx = fmaxf(ax[2 * q] * inv + bb[2 * q], 0.f);
      float hy = fmaxf(ax[2 * q + 1] * inv + bb[2 * q + 1], 0.f);
      u.h[q] = __floats2half2_rn(hx, hy);
    }
    outf[(size_t)w * 16 + f] = u.f4;
  }
}

// ---------------- GEMM2: hw2_16[M x 16] (fp16) = h16[M x 128] @ W2[128 x 16] ----------

__global__ __launch_bounds__(256) void gemm2_kernel(
    const __half* __restrict__ H16, const float* __restrict__ W2,
    __half2* __restrict__ O16, int M) {
  __shared__ float ws2[128 * 16];
  const int t = threadIdx.x;
#pragma unroll
  for (int i = 0; i < 8; ++i) ws2[i * 256 + t] = W2[i * 256 + t];
  __syncthreads();

  int r0 = blockIdx.x * 512 + t;
  int r1 = r0 + 256;
  bool v0 = r0 < M, v1 = r1 < M;
  const __half2* h0 = (const __half2*)(H16 + (size_t)r0 * 128);
  const __half2* h1 = (const __half2*)(H16 + (size_t)r1 * 128);

  float4 acc0[4], acc1[4];
#pragma unroll
  for (int q = 0; q < 4; ++q) {
    acc0[q] = make_float4(0.f, 0.f, 0.f, 0.f);
    acc1[q] = make_float4(0.f, 0.f, 0.f, 0.f);
  }

  for (int k4 = 0; k4 < 32; ++k4) {
    float2 f00 = make_float2(0.f, 0.f), f01 = make_float2(0.f, 0.f);
    float2 f10 = make_float2(0.f, 0.f), f11 = make_float2(0.f, 0.f);
    if (v0) { f00 = __half22float2(h0[2 * k4]); f01 = __half22float2(h0[2 * k4 + 1]); }
    if (v1) { f10 = __half22float2(h1[2 * k4]); f11 = __half22float2(h1[2 * k4 + 1]); }
    const float a0s[4] = {f00.x, f00.y, f01.x, f01.y};
    const float a1s[4] = {f10.x, f10.y, f11.x, f11.y};
#pragma unroll
    for (int j = 0; j < 4; ++j) {
      int k = k4 * 4 + j;
#pragma unroll
      for (int q = 0; q < 4; ++q) {
        float4 b = *(const float4*)&ws2[k * 16 + q * 4];
        acc0[q].x = fmaf(a0s[j], b.x, acc0[q].x);
        acc0[q].y = fmaf(a0s[j], b.y, acc0[q].y);
        acc0[q].z = fmaf(a0s[j], b.z, acc0[q].z);
        acc0[q].w = fmaf(a0s[j], b.w, acc0[q].w);
        acc1[q].x = fmaf(a1s[j], b.x, acc1[q].x);
        acc1[q].y = fmaf(a1s[j], b.y, acc1[q].y);
        acc1[q].z = fmaf(a1s[j], b.z, acc1[q].z);
        acc1[q].w = fmaf(a1s[j], b.w, acc1[q].w);
      }
    }
  }
  if (v0) {
    __half2* op = O16 + (size_t)r0 * 8;
#pragma unroll
    for (int q = 0; q < 4; ++q) {
      op[q * 2]     = __floats2half2_rn(acc0[q].x, acc0[q].y);
      op[q * 2 + 1] = __floats2half2_rn(acc0[q].z, acc0[q].w);
    }
  }
  if (v1) {
    __half2* op = O16 + (size_t)r1 * 8;
#pragma unroll
    for (int q = 0; q < 4; ++q) {
      op[q * 2]     = __floats2half2_rn(acc1[q].x, acc1[q].y);
      op[q * 2 + 1] = __floats2half2_rn(acc1[q].z, acc1[q].w);
    }
  }
}

// ---------------- F=16 aggregation ----------------

__global__ __launch_bounds__(256) void edge_agg16_kernel(
    const __half* __restrict__ feat, const int* __restrict__ nbr,
    const int* __restrict__ off, float* __restrict__ outf, int nseg) {
  int gid = blockIdx.x * 256 + threadIdx.x;
  int seg = gid >> 4;
  int c = gid & 15;
  if (seg >= nseg) return;
  int beg = off[seg], end = off[seg + 1];
  float a0 = 0.f, a1 = 0.f, a2 = 0.f, a3 = 0.f;
  int j = beg;
  for (; j + 8 <= end; j += 8) {
    int n0 = nbr[j],     n1 = nbr[j + 1], n2 = nbr[j + 2], n3 = nbr[j + 3];
    int n4 = nbr[j + 4], n5 = nbr[j + 5], n6 = nbr[j + 6], n7 = nbr[j + 7];
    float v0 = __half2float(feat[(size_t)n0 * 16 + c]);
    float v1 = __half2float(feat[(size_t)n1 * 16 + c]);
    float v2 = __half2float(feat[(size_t)n2 * 16 + c]);
    float v3 = __half2float(feat[(size_t)n3 * 16 + c]);
    float v4 = __half2float(feat[(size_t)n4 * 16 + c]);
    float v5 = __half2float(feat[(size_t)n5 * 16 + c]);
    float v6 = __half2float(feat[(size_t)n6 * 16 + c]);
    float v7 = __half2float(feat[(size_t)n7 * 16 + c]);
    a0 += v0 + v4; a1 += v1 + v5; a2 += v2 + v6; a3 += v3 + v7;
  }
  for (; j < end; ++j) a0 += __half2float(feat[(size_t)nbr[j] * 16 + c]);
  float inv = (end > beg) ? 1.f / (float)(end - beg) : 0.f;
  outf[(size_t)seg * 16 + c] = ((a0 + a1) + (a2 + a3)) * inv;
}

__global__ __launch_bounds__(256) void node_agg16_kernel(
    const float* __restrict__ feat, const ushort16_t* __restrict__ nbr,
    const int* __restrict__ off, const float* __restrict__ bias,
    float* __restrict__ outf, int nseg) {
  int gid = blockIdx.x * 256 + threadIdx.x;
  int seg = gid >> 4;
  int c = gid & 15;
  if (seg >= nseg) return;
  int beg = off[seg], end = off[seg + 1];
  float a0 = 0.f, a1 = 0.f, a2 = 0.f, a3 = 0.f;
  int j = beg;
  for (; j + 8 <= end; j += 8) {
    int n0 = nbr[j],     n1 = nbr[j + 1], n2 = nbr[j + 2], n3 = nbr[j + 3];
    int n4 = nbr[j + 4], n5 = nbr[j + 5], n6 = nbr[j + 6], n7 = nbr[j + 7];
    float v0 = feat[(size_t)n0 * 16 + c];
    float v1 = feat[(size_t)n1 * 16 + c];
    float v2 = feat[(size_t)n2 * 16 + c];
    float v3 = feat[(size_t)n3 * 16 + c];
    float v4 = feat[(size_t)n4 * 16 + c];
    float v5 = feat[(size_t)n5 * 16 + c];
    float v6 = feat[(size_t)n6 * 16 + c];
    float v7 = feat[(size_t)n7 * 16 + c];
    a0 += v0 + v4; a1 += v1 + v5; a2 += v2 + v6; a3 += v3 + v7;
  }
  for (; j < end; ++j) a0 += feat[(size_t)nbr[j] * 16 + c];
  float inv = (end > beg) ? 1.f / (float)(end - beg) : 0.f;
  outf[(size_t)seg * 16 + c] = ((a0 + a1) + (a2 + a3)) * inv + bias[c];
}

// ---------------- launch ----------------

extern "C" void kernel_launch(void* const* d_in, const int* in_sizes, int n_in,
                              void* d_out, int out_size, void* d_ws, size_t ws_size,
                              hipStream_t stream) {
  const float* x        = (const float*)d_in[0];
  const int*   node_idx = (const int*)d_in[1];
  const int*   edge_idx = (const int*)d_in[2];
  const float* W1 = (const float*)d_in[4];
  const float* b1 = (const float*)d_in[5];
  const float* W2 = (const float*)d_in[6];
  const float* b2 = (const float*)d_in[7];
  float* out = (float*)d_out;

  const int n_nodes = in_sizes[0] / F1;  // 100000
  const int nnz     = in_sizes[1];       // 1600000
  const int n_edges = N_EDGES_C;         // 50000
  const int nC      = (nnz + CHUNK - 1) / CHUNK;   // 391
  const int Le      = EBINS * nC;
  const int Ln      = NBINS * nC;
  const int nbE     = (Le + 1023) / 1024;
  const int nbN     = (Ln + 1023) / 1024;

  char* ws = (char*)d_ws;
  unsigned* epairs = (unsigned*)(ws + 0);        //  6.4M transient (packed u32)
  unsigned* npairs = (unsigned*)(ws + 6400000);  //  6.4M transient (packed u32)
  __half*  h16    = (__half*)(ws + 0);           // 25.6M flat (after bin_scatter)
  __half*  xw16   = (__half*)(ws + 25600000);    // 25.6M flat
  __half*  ef16   = (__half*)(ws + 51200000);    // 12.8M flat
  __half*  hw216  = (__half*)(ws + 64000000);    //  3.2M fp16
  float*   ef2    = (float*)(ws + 70400000);     //  3.2M
  int*     enbr   = (int*)(ws + 73600000);       //  6.4M (node ids)
  ushort16_t* nnbr16 = (ushort16_t*)(ws + 80000000); // 3.2M (edge ids, u16)
  int*     eoff   = (int*)(ws + 86400000);
  int*     noff   = (int*)(ws + 86600008);
  int*     echunkcnt = (int*)(ws + 87000016);
  int*     nchunkcnt = (int*)(ws + 87611540);
  int*     erunoff   = (int*)(ws + 88223064);
  int*     nrunoff   = (int*)(ws + 88834588);
  int*     ebinbase  = (int*)(ws + 89446112);
  int*     nbinbase  = (int*)(ws + 89447680);
  int*     epart     = (int*)(ws + 89449248);
  int*     npart     = (int*)(ws + 89450272);
  __half*  w1t16     = (__half*)(ws + 89451520); // 32,768 -> end 89,484,288

  w1t_kernel<<<64, 256, 0, stream>>>(W1, w1t16);

  hist_chunk_kernel<<<nC, 256, 0, stream>>>(node_idx, edge_idx,
                                            echunkcnt, nchunkcnt, nnz);
  cscan_p1_kernel<<<nbE + nbN, 256, 0, stream>>>(echunkcnt, nchunkcnt,
                                                 epart, npart, Le, Ln, nbE);
  cscan_p2_kernel<<<1, 256, 0, stream>>>(epart, npart, ebinbase, nbinbase,
                                         nbE, nbN, nnz);
  cscan_p3_kernel<<<nbE + nbN, 256, 0, stream>>>(echunkcnt, nchunkcnt,
                                                 epart, npart, erunoff, nrunoff,
                                                 ebinbase, nbinbase, Le, Ln, nbE, nC);
  stage_kernel<<<nC, 256, 0, stream>>>(node_idx, edge_idx, erunoff, nrunoff,
                                       epairs, npairs, nnz);
  bin_scatter_kernel<<<EBINS + NBINS, 256, 0, stream>>>(epairs, npairs,
                                                        ebinbase, nbinbase,
                                                        eoff, noff, enbr, nnbr16,
                                                        n_edges, n_nodes);

  // layer 1 (fp16 flat message path)
  gemm1_kernel<<<(n_nodes + 63) / 64, 256, 0, stream>>>(x, w1t16, xw16, n_nodes);
  edge_agg128_kernel<<<(n_edges * 64 + 255) / 256, 256, 0, stream>>>(
      (const float4*)xw16, enbr, eoff, (float4*)ef16, n_edges);
  node_agg128_kernel<<<(n_nodes * 64 + 255) / 256, 256, 0, stream>>>(
      (const float4*)ef16, nnbr16, noff, b1, (float4*)h16, n_nodes);

  // layer 2
  gemm2_kernel<<<(n_nodes + 511) / 512, 256, 0, stream>>>(h16, W2,
                                                          (__half2*)hw216, n_nodes);
  edge_agg16_kernel<<<(n_edges * 16 + 255) / 256, 256, 0, stream>>>(
      hw216, enbr, eoff, ef2, n_edges);
  node_agg16_kernel<<<(n_nodes * 16 + 255) / 256, 256, 0, stream>>>(
      ef2, nnbr16, noff, b2, out, n_nodes);
}

// Round 6
// 355.443 us; speedup vs baseline: 1.0543x; 1.0543x over previous
//
#include <hip/hip_runtime.h>
#include <hip/hip_fp16.h>

// N_NODES=100000, N_EDGES=50000, NNZ=1600000, dims 128->128->16, fp32 I/O.
// Message path fp16 (flat [row][128]), accumulate fp32. CSR: LDS-only counting sort.
// R12: staged pairs packed to u32; nnbr u16. (374 -> 364.5 us)
// R13/14 POST-MORTEM: 8-deep unroll never ran (mean deg 16 < stride 32) -> serial
// tail; VGPR=20 showed compiler serialized loads. REGRESSED 57.8->66.3.
// R15: predicated clamped gathers (no serial tail; invalid slots load end-1 and
// get weight 0 via v_fma_mix), depth 4 (node, ~deg 16) / 8 (edge, ~deg 32);
// asm keep-alive fence after loads forces all gathers in flight.

#define N_EDGES_C 50000
#define F1 128
#define F2 16
#define CHUNK 4096
#define EBIN_SHIFT 7
#define NBIN_SHIFT 8
#define EBINS 391
#define NBINS 391

typedef __attribute__((ext_vector_type(8))) _Float16 half8;
typedef __attribute__((ext_vector_type(4))) float f32x4;
typedef unsigned short ushort16_t;

// ---------------- CSR build ----------------

__global__ __launch_bounds__(256) void hist_chunk_kernel(
    const int* __restrict__ node_idx, const int* __restrict__ edge_idx,
    int* __restrict__ echunkcnt, int* __restrict__ nchunkcnt, int nnz) {
  __shared__ int ebc[EBINS], nbc[NBINS];
  const int t = threadIdx.x;
  for (int b = t; b < EBINS; b += 256) ebc[b] = 0;
  for (int b = t; b < NBINS; b += 256) nbc[b] = 0;
  __syncthreads();
  const int base = blockIdx.x * CHUNK;
  int end = base + CHUNK; if (end > nnz) end = nnz;
  for (int i = base + t; i < end; i += 256) {
    atomicAdd(&ebc[edge_idx[i] >> EBIN_SHIFT], 1);
    atomicAdd(&nbc[node_idx[i] >> NBIN_SHIFT], 1);
  }
  __syncthreads();
  const int nC = gridDim.x;
  for (int b = t; b < EBINS; b += 256) echunkcnt[b * nC + blockIdx.x] = ebc[b];
  for (int b = t; b < NBINS; b += 256) nchunkcnt[b * nC + blockIdx.x] = nbc[b];
}

__global__ __launch_bounds__(256) void cscan_p1_kernel(
    const int* __restrict__ ecc, const int* __restrict__ ncc,
    int* __restrict__ epart, int* __restrict__ npart,
    int Le, int Ln, int nbE) {
  __shared__ int red[256];
  const int t = threadIdx.x;
  const int b = blockIdx.x;
  const int* src; int L; int* dst; int bb;
  if (b < nbE) { src = ecc; L = Le; dst = epart; bb = b; }
  else         { src = ncc; L = Ln; dst = npart; bb = b - nbE; }
  int base = bb * 1024 + t * 4;
  int s = 0;
#pragma unroll
  for (int j = 0; j < 4; ++j) { int i = base + j; if (i < L) s += src[i]; }
  red[t] = s;
  __syncthreads();
  for (int d = 128; d > 0; d >>= 1) {
    if (t < d) red[t] += red[t + d];
    __syncthreads();
  }
  if (t == 0) dst[bb] = red[0];
}

__global__ __launch_bounds__(256) void cscan_p2_kernel(
    int* __restrict__ epart, int* __restrict__ npart,
    int* __restrict__ ebinbase, int* __restrict__ nbinbase,
    int nbE, int nbN, int nnz) {
  __shared__ int se[256], sn[256];
  const int t = threadIdx.x;
  se[t] = (t < nbE) ? epart[t] : 0;
  sn[t] = (t < nbN) ? npart[t] : 0;
  __syncthreads();
  for (int d = 1; d < 256; d <<= 1) {
    int ve = (t >= d) ? se[t - d] : 0;
    int vn = (t >= d) ? sn[t - d] : 0;
    __syncthreads();
    se[t] += ve; sn[t] += vn;
    __syncthreads();
  }
  if (t < nbE) epart[t] = (t > 0) ? se[t - 1] : 0;
  if (t < nbN) npart[t] = (t > 0) ? sn[t - 1] : 0;
  if (t == 0) { ebinbase[EBINS] = nnz; nbinbase[NBINS] = nnz; }
}

__global__ __launch_bounds__(256) void cscan_p3_kernel(
    const int* __restrict__ ecc, const int* __restrict__ ncc,
    const int* __restrict__ epart, const int* __restrict__ npart,
    int* __restrict__ erunoff, int* __restrict__ nrunoff,
    int* __restrict__ ebinbase, int* __restrict__ nbinbase,
    int Le, int Ln, int nbE, int nC) {
  __shared__ int red[256];
  const int t = threadIdx.x;
  const int b = blockIdx.x;
  const int* src; const int* part; int L; int* ro; int* bba; int bb;
  if (b < nbE) { src = ecc; part = epart; L = Le; ro = erunoff; bba = ebinbase; bb = b; }
  else         { src = ncc; part = npart; L = Ln; ro = nrunoff; bba = nbinbase; bb = b - nbE; }
  int base = bb * 1024 + t * 4;
  int v[4]; int s = 0;
#pragma unroll
  for (int j = 0; j < 4; ++j) { int i = base + j; v[j] = (i < L) ? src[i] : 0; s += v[j]; }
  red[t] = s;
  __syncthreads();
  for (int d = 1; d < 256; d <<= 1) {
    int x = (t >= d) ? red[t - d] : 0;
    __syncthreads();
    red[t] += x;
    __syncthreads();
  }
  int run = part[bb] + ((t > 0) ? red[t - 1] : 0);
#pragma unroll
  for (int j = 0; j < 4; ++j) {
    int i = base + j;
    if (i < L) {
      ro[i] = run;
      if (i % nC == 0) bba[i / nC] = run;
      run += v[j];
    }
  }
}

// stage: pack pairs into u32. e-side: (n<<7)|(e&127)  [17+7=24 bits]
//                             n-side: (e<<8)|(n&255)  [16+8=24 bits]

__global__ __launch_bounds__(256) void stage_kernel(
    const int* __restrict__ node_idx, const int* __restrict__ edge_idx,
    const int* __restrict__ erunoff, const int* __restrict__ nrunoff,
    unsigned* __restrict__ epairs, unsigned* __restrict__ npairs, int nnz) {
  __shared__ int ecur[EBINS], ncur[NBINS];
  const int t = threadIdx.x;
  const int nC = gridDim.x;
  for (int b = t; b < EBINS; b += 256) ecur[b] = erunoff[b * nC + blockIdx.x];
  for (int b = t; b < NBINS; b += 256) ncur[b] = nrunoff[b * nC + blockIdx.x];
  __syncthreads();
  const int base = blockIdx.x * CHUNK;
  int end = base + CHUNK; if (end > nnz) end = nnz;
  for (int i = base + t; i < end; i += 256) {
    int e = edge_idx[i];
    int n = node_idx[i];
    int p = atomicAdd(&ecur[e >> EBIN_SHIFT], 1);
    epairs[p] = ((unsigned)n << 7) | (unsigned)(e & 127);
    int q = atomicAdd(&ncur[n >> NBIN_SHIFT], 1);
    npairs[q] = ((unsigned)e << 8) | (unsigned)(n & 255);
  }
}

__global__ __launch_bounds__(256) void bin_scatter_kernel(
    const unsigned* __restrict__ epairs, const unsigned* __restrict__ npairs,
    const int* __restrict__ ebinbase, const int* __restrict__ nbinbase,
    int* __restrict__ eoff, int* __restrict__ noff,
    int* __restrict__ enbr, ushort16_t* __restrict__ nnbr,
    int n_edges, int n_nodes) {
  __shared__ int cnt[256];
  __shared__ int scn[256];
  const int bid = blockIdx.x;
  const int t = threadIdx.x;
  if (bid < EBINS) {
    const int e0 = bid << EBIN_SHIFT;
    const int ne = min(1 << EBIN_SHIFT, n_edges - e0);
    const int beg = ebinbase[bid], end = ebinbase[bid + 1];
    if (t < 128) cnt[t] = 0;
    __syncthreads();
    for (int j = beg + t; j < end; j += 256) atomicAdd(&cnt[epairs[j] & 127u], 1);
    __syncthreads();
    if (t < 128) scn[t] = cnt[t];
    __syncthreads();
    for (int d = 1; d < 128; d <<= 1) {
      int x = 0;
      if (t < 128 && t >= d) x = scn[t - d];
      __syncthreads();
      if (t < 128) scn[t] += x;
      __syncthreads();
    }
    int pos0 = 0;
    if (t < 128) {
      int excl = (t > 0) ? scn[t - 1] : 0;
      pos0 = beg + excl;
      if (t < ne) eoff[e0 + t] = pos0;
    }
    __syncthreads();
    if (t < 128) scn[t] = pos0;
    __syncthreads();
    for (int j = beg + t; j < end; j += 256) {
      unsigned p = epairs[j];
      int pos = atomicAdd(&scn[p & 127u], 1);
      enbr[pos] = (int)(p >> 7);
    }
    if (bid == EBINS - 1 && t == 0) eoff[n_edges] = end;
  } else {
    const int b = bid - EBINS;
    const int n0 = b << NBIN_SHIFT;
    const int nn = min(1 << NBIN_SHIFT, n_nodes - n0);
    const int beg = nbinbase[b], end = nbinbase[b + 1];
    cnt[t] = 0;
    __syncthreads();
    for (int j = beg + t; j < end; j += 256) atomicAdd(&cnt[npairs[j] & 255u], 1);
    __syncthreads();
    scn[t] = cnt[t];
    __syncthreads();
    for (int d = 1; d < 256; d <<= 1) {
      int x = (t >= d) ? scn[t - d] : 0;
      __syncthreads();
      scn[t] += x;
      __syncthreads();
    }
    int excl = (t > 0) ? scn[t - 1] : 0;
    int pos0 = beg + excl;
    if (t < nn) noff[n0 + t] = pos0;
    __syncthreads();
    scn[t] = pos0;
    __syncthreads();
    for (int j = beg + t; j < end; j += 256) {
      unsigned p = npairs[j];
      int pos = atomicAdd(&scn[p & 255u], 1);
      nnbr[pos] = (ushort16_t)(p >> 8);   // edge id < 50000 -> u16
    }
    if (bid == EBINS + NBINS - 1 && t == 0) noff[n_nodes] = end;
  }
}

// ---------------- W1 transpose+convert: W1t16[n][k] = fp16(W1[k][n]) ----------------

__global__ __launch_bounds__(256) void w1t_kernel(
    const float* __restrict__ W1, __half* __restrict__ W1t) {
  int i = blockIdx.x * 256 + threadIdx.x;   // 0..16383
  int n = i >> 7, k = i & 127;
  W1t[i] = __float2half(W1[k * 128 + n]);
}

// ---------------- GEMM1 (MFMA): xw16[M x 128] = fp16(x) @ fp16(W1) ----------------
// 256 thr = 4 waves; block tile 64(M) x 128(N); K=128 in 4 chunks of 32.

__global__ __launch_bounds__(256) void gemm1_kernel(
    const float* __restrict__ A, const __half* __restrict__ W1t16,
    __half* __restrict__ C16, int M) {
  __shared__ _Float16 As[64 * 136];
  __shared__ _Float16 Bs[128 * 136];
  const int t = threadIdx.x;
  const int bm = blockIdx.x * 64;

#pragma unroll
  for (int i = 0; i < 8; ++i) {
    int lin = i * 256 + t;
    int row = lin >> 5;
    int c4 = lin & 31;
    int grow = bm + row;
    float4 v = make_float4(0.f, 0.f, 0.f, 0.f);
    if (grow < M) v = *(const float4*)(A + (size_t)grow * 128 + c4 * 4);
    _Float16* dst = &As[row * 136 + c4 * 4];
    dst[0] = (_Float16)v.x; dst[1] = (_Float16)v.y;
    dst[2] = (_Float16)v.z; dst[3] = (_Float16)v.w;
  }
#pragma unroll
  for (int i = 0; i < 8; ++i) {
    int lin = i * 256 + t;
    int n = lin >> 4;
    int c = lin & 15;
    *(float4*)&Bs[n * 136 + c * 8] = *(const float4*)(W1t16 + n * 128 + c * 8);
  }
  __syncthreads();

  const int w = t >> 6;
  const int lane = t & 63;
  const int l16 = lane & 15;
  const int quad = lane >> 4;

  f32x4 acc[8];
#pragma unroll
  for (int n = 0; n < 8; ++n) acc[n] = (f32x4){0.f, 0.f, 0.f, 0.f};

  const _Float16* arow = &As[(w * 16 + l16) * 136 + quad * 8];
#pragma unroll
  for (int kt = 0; kt < 4; ++kt) {
    half8 a = *(const half8*)(arow + kt * 32);
#pragma unroll
    for (int n = 0; n < 8; ++n) {
      half8 b = *(const half8*)&Bs[(n * 16 + l16) * 136 + kt * 32 + quad * 8];
      acc[n] = __builtin_amdgcn_mfma_f32_16x16x32_f16(a, b, acc[n], 0, 0, 0);
    }
  }
  __syncthreads();   // all frag reads done; reuse As as C-staging

  // C/D layout (m89-verified, dtype-independent): col=lane&15, row=quad*4+reg
#pragma unroll
  for (int n = 0; n < 8; ++n) {
#pragma unroll
    for (int r = 0; r < 4; ++r) {
      int row = w * 16 + quad * 4 + r;
      int col = n * 16 + l16;
      As[row * 136 + col] = (_Float16)acc[n][r];
    }
  }
  __syncthreads();

  // coalesced store: 64 rows x 16 chunks of 16B = 1024 / 256 = 4 iters
#pragma unroll
  for (int i = 0; i < 4; ++i) {
    int lin = i * 256 + t;
    int row = lin >> 4;
    int c = lin & 15;
    int grow = bm + row;
    if (grow < M)
      *(float4*)(C16 + (size_t)grow * 128 + c * 8) = *(const float4*)&As[row * 136 + c * 8];
  }
}

// ---------------- F=128 aggregation: predicated clamped gathers ----------------
// acc += fp16(v) * wt via v_fma_mix_f32 (wt=0 kills invalid slots; table values
// are finite so v*0 == 0 exactly).

__device__ __forceinline__ void acc_mixw(float* ax, f32x4 v, float wt) {
  const unsigned* w = (const unsigned*)&v;
#pragma unroll
  for (int q = 0; q < 4; ++q) {
    asm("v_fma_mix_f32 %0, %1, %2, %0 op_sel:[0,0,0] op_sel_hi:[1,0,0]"
        : "+v"(ax[2 * q]) : "v"(w[q]), "v"(wt));
    asm("v_fma_mix_f32 %0, %1, %2, %0 op_sel:[1,0,0] op_sel_hi:[1,0,0]"
        : "+v"(ax[2 * q + 1]) : "v"(w[q]), "v"(wt));
  }
}

// edge agg: mean degree 32 -> depth 8 (stride 32 over 4 r-lanes)
__global__ __launch_bounds__(256) void edge_agg128_kernel(
    const f32x4* __restrict__ feat,
    const int* __restrict__ nbr, const int* __restrict__ off,
    float4* __restrict__ outf, int nseg) {
  int w = (blockIdx.x * 256 + threadIdx.x) >> 6;
  if (w >= nseg) return;
  const int lane = threadIdx.x & 63;
  const int r = lane >> 4;
  const int f = lane & 15;
  int beg = off[w], end = off[w + 1];
  const int kl = end - 1;
  float ax[8];
#pragma unroll
  for (int i = 0; i < 8; ++i) ax[i] = 0.f;
  for (int k = beg + r; k < end; k += 32) {
    int k1 = min(k + 4, kl),  k2 = min(k + 8, kl),  k3 = min(k + 12, kl);
    int k4 = min(k + 16, kl), k5 = min(k + 20, kl), k6 = min(k + 24, kl), k7 = min(k + 28, kl);
    float w1 = (k + 4 <= kl) ? 1.f : 0.f;
    float w2 = (k + 8 <= kl) ? 1.f : 0.f;
    float w3 = (k + 12 <= kl) ? 1.f : 0.f;
    float w4 = (k + 16 <= kl) ? 1.f : 0.f;
    float w5 = (k + 20 <= kl) ? 1.f : 0.f;
    float w6 = (k + 24 <= kl) ? 1.f : 0.f;
    float w7 = (k + 28 <= kl) ? 1.f : 0.f;
    int n0 = nbr[k],  n1 = nbr[k1], n2 = nbr[k2], n3 = nbr[k3];
    int n4 = nbr[k4], n5 = nbr[k5], n6 = nbr[k6], n7 = nbr[k7];
    f32x4 v0 = feat[(size_t)n0 * 16 + f];
    f32x4 v1 = feat[(size_t)n1 * 16 + f];
    f32x4 v2 = feat[(size_t)n2 * 16 + f];
    f32x4 v3 = feat[(size_t)n3 * 16 + f];
    f32x4 v4 = feat[(size_t)n4 * 16 + f];
    f32x4 v5 = feat[(size_t)n5 * 16 + f];
    f32x4 v6 = feat[(size_t)n6 * 16 + f];
    f32x4 v7 = feat[(size_t)n7 * 16 + f];
    asm volatile("" :: "v"(v0), "v"(v1), "v"(v2), "v"(v3),
                       "v"(v4), "v"(v5), "v"(v6), "v"(v7));
    acc_mixw(ax, v0, 1.f); acc_mixw(ax, v1, w1);
    acc_mixw(ax, v2, w2);  acc_mixw(ax, v3, w3);
    acc_mixw(ax, v4, w4);  acc_mixw(ax, v5, w5);
    acc_mixw(ax, v6, w6);  acc_mixw(ax, v7, w7);
  }
#pragma unroll
  for (int i = 0; i < 8; ++i) {
    ax[i] += __shfl_xor(ax[i], 16, 64);
    ax[i] += __shfl_xor(ax[i], 32, 64);
  }
  if (r == 0) {
    float inv = (end > beg) ? 1.f / (float)(end - beg) : 0.f;
    union { float4 f4; __half2 h[4]; } u;
#pragma unroll
    for (int q = 0; q < 4; ++q)
      u.h[q] = __floats2half2_rn(ax[2 * q] * inv, ax[2 * q + 1] * inv);
    outf[(size_t)w * 16 + f] = u.f4;
  }
}

// node agg: mean degree 16 -> depth 4 (stride 16 over 4 r-lanes)
__global__ __launch_bounds__(256) void node_agg128_kernel(
    const f32x4* __restrict__ feat,
    const ushort16_t* __restrict__ nbr, const int* __restrict__ off,
    const float* __restrict__ bias,
    float4* __restrict__ outf, int nseg) {
  int w = (blockIdx.x * 256 + threadIdx.x) >> 6;
  if (w >= nseg) return;
  const int lane = threadIdx.x & 63;
  const int r = lane >> 4;
  const int f = lane & 15;
  int beg = off[w], end = off[w + 1];
  const int kl = end - 1;
  float ax[8];
#pragma unroll
  for (int i = 0; i < 8; ++i) ax[i] = 0.f;
  for (int k = beg + r; k < end; k += 16) {
    int k1 = min(k + 4, kl), k2 = min(k + 8, kl), k3 = min(k + 12, kl);
    float w1 = (k + 4 <= kl) ? 1.f : 0.f;
    float w2 = (k + 8 <= kl) ? 1.f : 0.f;
    float w3 = (k + 12 <= kl) ? 1.f : 0.f;
    int e0 = nbr[k], e1 = nbr[k1], e2 = nbr[k2], e3 = nbr[k3];
    f32x4 v0 = feat[(size_t)e0 * 16 + f];
    f32x4 v1 = feat[(size_t)e1 * 16 + f];
    f32x4 v2 = feat[(size_t)e2 * 16 + f];
    f32x4 v3 = feat[(size_t)e3 * 16 + f];
    asm volatile("" :: "v"(v0), "v"(v1), "v"(v2), "v"(v3));
    acc_mixw(ax, v0, 1.f); acc_mixw(ax, v1, w1);
    acc_mixw(ax, v2, w2);  acc_mixw(ax, v3, w3);
  }
#pragma unroll
  for (int i = 0; i < 8; ++i) {
    ax[i] += __shfl_xor(ax[i], 16, 64);
    ax[i] += __shfl_xor(ax[i], 32, 64);
  }
  if (r == 0) {
    float inv = (end > beg) ? 1.f / (float)(end - beg) : 0.f;
    float4 blo = ((const float4*)bias)[2 * f];
    float4 bhi = ((const float4*)bias)[2 * f + 1];
    float bb[8] = {blo.x, blo.y, blo.z, blo.w, bhi.x, bhi.y, bhi.z, bhi.w};
    union { float4 f4; __half2 h[4]; } u;
#pragma unroll
    for (int q = 0; q < 4; ++q) {
      float hx = fmaxf(ax[2 * q] * inv + bb[2 * q], 0.f);
      float hy = fmaxf(ax[2 * q + 1] * inv + bb[2 * q + 1], 0.f);
      u.h[q] = __floats2half2_rn(hx, hy);
    }
    outf[(size_t)w * 16 + f] = u.f4;
  }
}

// ---------------- GEMM2: hw2_16[M x 16] (fp16) = h16[M x 128] @ W2[128 x 16] ----------

__global__ __launch_bounds__(256) void gemm2_kernel(
    const __half* __restrict__ H16, const float* __restrict__ W2,
    __half2* __restrict__ O16, int M) {
  __shared__ float ws2[128 * 16];
  const int t = threadIdx.x;
#pragma unroll
  for (int i = 0; i < 8; ++i) ws2[i * 256 + t] = W2[i * 256 + t];
  __syncthreads();

  int r0 = blockIdx.x * 512 + t;
  int r1 = r0 + 256;
  bool v0 = r0 < M, v1 = r1 < M;
  const __half2* h0 = (const __half2*)(H16 + (size_t)r0 * 128);
  const __half2* h1 = (const __half2*)(H16 + (size_t)r1 * 128);

  float4 acc0[4], acc1[4];
#pragma unroll
  for (int q = 0; q < 4; ++q) {
    acc0[q] = make_float4(0.f, 0.f, 0.f, 0.f);
    acc1[q] = make_float4(0.f, 0.f, 0.f, 0.f);
  }

  for (int k4 = 0; k4 < 32; ++k4) {
    float2 f00 = make_float2(0.f, 0.f), f01 = make_float2(0.f, 0.f);
    float2 f10 = make_float2(0.f, 0.f), f11 = make_float2(0.f, 0.f);
    if (v0) { f00 = __half22float2(h0[2 * k4]); f01 = __half22float2(h0[2 * k4 + 1]); }
    if (v1) { f10 = __half22float2(h1[2 * k4]); f11 = __half22float2(h1[2 * k4 + 1]); }
    const float a0s[4] = {f00.x, f00.y, f01.x, f01.y};
    const float a1s[4] = {f10.x, f10.y, f11.x, f11.y};
#pragma unroll
    for (int j = 0; j < 4; ++j) {
      int k = k4 * 4 + j;
#pragma unroll
      for (int q = 0; q < 4; ++q) {
        float4 b = *(const float4*)&ws2[k * 16 + q * 4];
        acc0[q].x = fmaf(a0s[j], b.x, acc0[q].x);
        acc0[q].y = fmaf(a0s[j], b.y, acc0[q].y);
        acc0[q].z = fmaf(a0s[j], b.z, acc0[q].z);
        acc0[q].w = fmaf(a0s[j], b.w, acc0[q].w);
        acc1[q].x = fmaf(a1s[j], b.x, acc1[q].x);
        acc1[q].y = fmaf(a1s[j], b.y, acc1[q].y);
        acc1[q].z = fmaf(a1s[j], b.z, acc1[q].z);
        acc1[q].w = fmaf(a1s[j], b.w, acc1[q].w);
      }
    }
  }
  if (v0) {
    __half2* op = O16 + (size_t)r0 * 8;
#pragma unroll
    for (int q = 0; q < 4; ++q) {
      op[q * 2]     = __floats2half2_rn(acc0[q].x, acc0[q].y);
      op[q * 2 + 1] = __floats2half2_rn(acc0[q].z, acc0[q].w);
    }
  }
  if (v1) {
    __half2* op = O16 + (size_t)r1 * 8;
#pragma unroll
    for (int q = 0; q < 4; ++q) {
      op[q * 2]     = __floats2half2_rn(acc1[q].x, acc1[q].y);
      op[q * 2 + 1] = __floats2half2_rn(acc1[q].z, acc1[q].w);
    }
  }
}

// ---------------- F=16 aggregation ----------------

__global__ __launch_bounds__(256) void edge_agg16_kernel(
    const __half* __restrict__ feat, const int* __restrict__ nbr,
    const int* __restrict__ off, float* __restrict__ outf, int nseg) {
  int gid = blockIdx.x * 256 + threadIdx.x;
  int seg = gid >> 4;
  int c = gid & 15;
  if (seg >= nseg) return;
  int beg = off[seg], end = off[seg + 1];
  float a0 = 0.f, a1 = 0.f, a2 = 0.f, a3 = 0.f;
  int j = beg;
  for (; j + 8 <= end; j += 8) {
    int n0 = nbr[j],     n1 = nbr[j + 1], n2 = nbr[j + 2], n3 = nbr[j + 3];
    int n4 = nbr[j + 4], n5 = nbr[j + 5], n6 = nbr[j + 6], n7 = nbr[j + 7];
    float v0 = __half2float(feat[(size_t)n0 * 16 + c]);
    float v1 = __half2float(feat[(size_t)n1 * 16 + c]);
    float v2 = __half2float(feat[(size_t)n2 * 16 + c]);
    float v3 = __half2float(feat[(size_t)n3 * 16 + c]);
    float v4 = __half2float(feat[(size_t)n4 * 16 + c]);
    float v5 = __half2float(feat[(size_t)n5 * 16 + c]);
    float v6 = __half2float(feat[(size_t)n6 * 16 + c]);
    float v7 = __half2float(feat[(size_t)n7 * 16 + c]);
    a0 += v0 + v4; a1 += v1 + v5; a2 += v2 + v6; a3 += v3 + v7;
  }
  for (; j < end; ++j) a0 += __half2float(feat[(size_t)nbr[j] * 16 + c]);
  float inv = (end > beg) ? 1.f / (float)(end - beg) : 0.f;
  outf[(size_t)seg * 16 + c] = ((a0 + a1) + (a2 + a3)) * inv;
}

__global__ __launch_bounds__(256) void node_agg16_kernel(
    const float* __restrict__ feat, const ushort16_t* __restrict__ nbr,
    const int* __restrict__ off, const float* __restrict__ bias,
    float* __restrict__ outf, int nseg) {
  int gid = blockIdx.x * 256 + threadIdx.x;
  int seg = gid >> 4;
  int c = gid & 15;
  if (seg >= nseg) return;
  int beg = off[seg], end = off[seg + 1];
  float a0 = 0.f, a1 = 0.f, a2 = 0.f, a3 = 0.f;
  int j = beg;
  for (; j + 8 <= end; j += 8) {
    int n0 = nbr[j],     n1 = nbr[j + 1], n2 = nbr[j + 2], n3 = nbr[j + 3];
    int n4 = nbr[j + 4], n5 = nbr[j + 5], n6 = nbr[j + 6], n7 = nbr[j + 7];
    float v0 = feat[(size_t)n0 * 16 + c];
    float v1 = feat[(size_t)n1 * 16 + c];
    float v2 = feat[(size_t)n2 * 16 + c];
    float v3 = feat[(size_t)n3 * 16 + c];
    float v4 = feat[(size_t)n4 * 16 + c];
    float v5 = feat[(size_t)n5 * 16 + c];
    float v6 = feat[(size_t)n6 * 16 + c];
    float v7 = feat[(size_t)n7 * 16 + c];
    a0 += v0 + v4; a1 += v1 + v5; a2 += v2 + v6; a3 += v3 + v7;
  }
  for (; j < end; ++j) a0 += feat[(size_t)nbr[j] * 16 + c];
  float inv = (end > beg) ? 1.f / (float)(end - beg) : 0.f;
  outf[(size_t)seg * 16 + c] = ((a0 + a1) + (a2 + a3)) * inv + bias[c];
}

// ---------------- launch ----------------

extern "C" void kernel_launch(void* const* d_in, const int* in_sizes, int n_in,
                              void* d_out, int out_size, void* d_ws, size_t ws_size,
                              hipStream_t stream) {
  const float* x        = (const float*)d_in[0];
  const int*   node_idx = (const int*)d_in[1];
  const int*   edge_idx = (const int*)d_in[2];
  const float* W1 = (const float*)d_in[4];
  const float* b1 = (const float*)d_in[5];
  const float* W2 = (const float*)d_in[6];
  const float* b2 = (const float*)d_in[7];
  float* out = (float*)d_out;

  const int n_nodes = in_sizes[0] / F1;  // 100000
  const int nnz     = in_sizes[1];       // 1600000
  const int n_edges = N_EDGES_C;         // 50000
  const int nC      = (nnz + CHUNK - 1) / CHUNK;   // 391
  const int Le      = EBINS * nC;
  const int Ln      = NBINS * nC;
  const int nbE     = (Le + 1023) / 1024;
  const int nbN     = (Ln + 1023) / 1024;

  char* ws = (char*)d_ws;
  unsigned* epairs = (unsigned*)(ws + 0);        //  6.4M transient (packed u32)
  unsigned* npairs = (unsigned*)(ws + 6400000);  //  6.4M transient (packed u32)
  __half*  h16    = (__half*)(ws + 0);           // 25.6M flat (after bin_scatter)
  __half*  xw16   = (__half*)(ws + 25600000);    // 25.6M flat
  __half*  ef16   = (__half*)(ws + 51200000);    // 12.8M flat
  __half*  hw216  = (__half*)(ws + 64000000);    //  3.2M fp16
  float*   ef2    = (float*)(ws + 70400000);     //  3.2M
  int*     enbr   = (int*)(ws + 73600000);       //  6.4M (node ids)
  ushort16_t* nnbr16 = (ushort16_t*)(ws + 80000000); // 3.2M (edge ids, u16)
  int*     eoff   = (int*)(ws + 86400000);
  int*     noff   = (int*)(ws + 86600008);
  int*     echunkcnt = (int*)(ws + 87000016);
  int*     nchunkcnt = (int*)(ws + 87611540);
  int*     erunoff   = (int*)(ws + 88223064);
  int*     nrunoff   = (int*)(ws + 88834588);
  int*     ebinbase  = (int*)(ws + 89446112);
  int*     nbinbase  = (int*)(ws + 89447680);
  int*     epart     = (int*)(ws + 89449248);
  int*     npart     = (int*)(ws + 89450272);
  __half*  w1t16     = (__half*)(ws + 89451520); // 32,768 -> end 89,484,288

  w1t_kernel<<<64, 256, 0, stream>>>(W1, w1t16);

  hist_chunk_kernel<<<nC, 256, 0, stream>>>(node_idx, edge_idx,
                                            echunkcnt, nchunkcnt, nnz);
  cscan_p1_kernel<<<nbE + nbN, 256, 0, stream>>>(echunkcnt, nchunkcnt,
                                                 epart, npart, Le, Ln, nbE);
  cscan_p2_kernel<<<1, 256, 0, stream>>>(epart, npart, ebinbase, nbinbase,
                                         nbE, nbN, nnz);
  cscan_p3_kernel<<<nbE + nbN, 256, 0, stream>>>(echunkcnt, nchunkcnt,
                                                 epart, npart, erunoff, nrunoff,
                                                 ebinbase, nbinbase, Le, Ln, nbE, nC);
  stage_kernel<<<nC, 256, 0, stream>>>(node_idx, edge_idx, erunoff, nrunoff,
                                       epairs, npairs, nnz);
  bin_scatter_kernel<<<EBINS + NBINS, 256, 0, stream>>>(epairs, npairs,
                                                        ebinbase, nbinbase,
                                                        eoff, noff, enbr, nnbr16,
                                                        n_edges, n_nodes);

  // layer 1 (fp16 flat message path)
  gemm1_kernel<<<(n_nodes + 63) / 64, 256, 0, stream>>>(x, w1t16, xw16, n_nodes);
  edge_agg128_kernel<<<(n_edges * 64 + 255) / 256, 256, 0, stream>>>(
      (const f32x4*)xw16, enbr, eoff, (float4*)ef16, n_edges);
  node_agg128_kernel<<<(n_nodes * 64 + 255) / 256, 256, 0, stream>>>(
      (const f32x4*)ef16, nnbr16, noff, b1, (float4*)h16, n_nodes);

  // layer 2
  gemm2_kernel<<<(n_nodes + 511) / 512, 256, 0, stream>>>(h16, W2,
                                                          (__half2*)hw216, n_nodes);
  edge_agg16_kernel<<<(n_edges * 16 + 255) / 256, 256, 0, stream>>>(
      hw216, enbr, eoff, ef2, n_edges);
  node_agg16_kernel<<<(n_nodes * 16 + 255) / 256, 256, 0, stream>>>(
      ef2, nnbr16, noff, b2, out, n_nodes);
}